// Round 1
// baseline (140.952 us; speedup 1.0000x reference)
//
#include <hip/hip_runtime.h>
#include <stdint.h>

typedef __bf16    bf16x8  __attribute__((ext_vector_type(8)));
typedef float     f32x16v __attribute__((ext_vector_type(16)));
typedef float     f32x4v  __attribute__((ext_vector_type(4)));
typedef float     f32x2v  __attribute__((ext_vector_type(2)));
typedef uint32_t  u32x4v  __attribute__((ext_vector_type(4)));
typedef unsigned short u16;

__device__ __forceinline__ u16 f32_to_bf16_rne(float f) {
  uint32_t u = __builtin_bit_cast(uint32_t, f);
  return (u16)((u + 0x7fffu + ((u >> 16) & 1u)) >> 16);
}

// prep: W f32 [65][i=64][k=64]  ->  w1t bf16 [65][k][i]  and  w2b bf16 [65][i][k]
__global__ __launch_bounds__(256) void prep_w(const float* __restrict__ W,
                                              u16* __restrict__ w1t,
                                              u16* __restrict__ w2b) {
  __shared__ u16 tile[64 * 65];
  const int j = blockIdx.x;
  const int t = threadIdx.x;
  const float* Wj = W + j * 4096;
  for (int idx = t; idx < 4096; idx += 256) {
    u16 us = f32_to_bf16_rne(Wj[idx]);
    w2b[j * 4096 + idx] = us;
    tile[(idx >> 6) * 65 + (idx & 63)] = us;   // tile[i][k]
  }
  __syncthreads();
  for (int idx = t; idx < 4096; idx += 256) {  // idx = k*64 + i
    w1t[j * 4096 + idx] = tile[(idx & 63) * 65 + (idx >> 6)];
  }
}

// main: grid 256 blocks (1/CU), 512 thr (8 waves), BB=128 samples/block.
// wave = (nt = n-tile of 32 cols) x (jq = quarter of the 65 j-chunks).
// Each wave: 4 sample-tiles of 32 rows, C = f32x16 acc[4].
__global__ __launch_bounds__(512, 2) void rquad_main(
    const float* __restrict__ x, const float* __restrict__ g,
    const u16* __restrict__ w1t, const u16* __restrict__ w2b,
    float* __restrict__ out) {
  __shared__ u16   x1l[128 * 66];   // x1 bf16, [sample][j0..64], col64 = 1.0
  __shared__ float vl[128 * 68];    // f32 combine buffer (v, then out)

  const int t    = threadIdx.x;
  const int lane = t & 63;
  const int wv   = t >> 6;
  const int nt   = wv & 1;          // n-tile (cols 32*nt .. +32)
  const int jq   = wv >> 1;         // j-quarter
  const int col  = lane & 31;
  const int half = lane >> 5;
  const long base = (long)blockIdx.x * 128;

  // fill x1 (bf16) + zero combine buffer
  for (int idx = t; idx < 128 * 64; idx += 512) {
    int s = idx >> 6, c = idx & 63;
    x1l[s * 66 + c] = f32_to_bf16_rne(x[(base + s) * 64 + c]);
  }
  if (t < 128) x1l[t * 66 + 64] = (u16)0x3F80;  // bias 1.0
  for (int idx = t; idx < 128 * 68; idx += 512) vl[idx] = 0.0f;

  // zr = per-lane K-side vector (g for pass 1, v for pass 2), f32 pairs.
  // zr[tt][s*4+q] = values at indices (s*16 + half*8 + 2q, +1) for sample tt*32+col
  f32x2v zr[4][16];
  #pragma unroll
  for (int tt = 0; tt < 4; ++tt) {
    const float* gp = g + (base + tt * 32 + col) * 64;
    #pragma unroll
    for (int s = 0; s < 4; ++s) {
      const int i0 = s * 16 + half * 8;
      f32x4v a = *reinterpret_cast<const f32x4v*>(gp + i0);
      f32x4v b = *reinterpret_cast<const f32x4v*>(gp + i0 + 4);
      zr[tt][s*4+0][0] = a[0]; zr[tt][s*4+0][1] = a[1];
      zr[tt][s*4+1][0] = a[2]; zr[tt][s*4+1][1] = a[3];
      zr[tt][s*4+2][0] = b[0]; zr[tt][s*4+2][1] = b[1];
      zr[tt][s*4+3][0] = b[2]; zr[tt][s*4+3][1] = b[3];
    }
  }

  const int j0 = jq * 16;
  const int j1 = (jq == 3) ? 65 : (j0 + 16);

  f32x16v acc[4];

  __syncthreads();

  auto run_pass = [&](const u16* __restrict__ Wsrc) {
    #pragma unroll
    for (int tt = 0; tt < 4; ++tt)
      #pragma unroll
      for (int r = 0; r < 16; ++r) acc[tt][r] = 0.0f;

    // per-lane B row pointer: row = nt*32+col, element offset half*8 (+ s*16 + jj*4096)
    const u16* wrow = Wsrc + (nt * 32 + col) * 64 + half * 8;

    for (int jj = j0; jj < j1; ++jj) {
      // B fragments: 4 contiguous 16B loads (L1/L2-resident stream)
      u32x4v bfr[4];
      #pragma unroll
      for (int s = 0; s < 4; ++s)
        bfr[s] = *reinterpret_cast<const u32x4v*>(wrow + jj * 4096 + s * 16);

      // x1[b, jj] broadcast per sample-tile
      f32x2v xx[4];
      #pragma unroll
      for (int tt = 0; tt < 4; ++tt) {
        u16 xu = x1l[(tt * 32 + col) * 66 + jj];
        float xf = __builtin_bit_cast(float, (uint32_t)xu << 16);
        xx[tt][0] = xf; xx[tt][1] = xf;
      }

      #pragma unroll
      for (int s = 0; s < 4; ++s) {
        #pragma unroll
        for (int tt = 0; tt < 4; ++tt) {
          // A-frag = bf16(x1 * zr): 4 pk_mul + 4 cvt_pk
          f32x2v m0, m1, m2, m3;
          asm("v_pk_mul_f32 %0, %1, %2" : "=v"(m0) : "v"(xx[tt]), "v"(zr[tt][s*4+0]));
          asm("v_pk_mul_f32 %0, %1, %2" : "=v"(m1) : "v"(xx[tt]), "v"(zr[tt][s*4+1]));
          asm("v_pk_mul_f32 %0, %1, %2" : "=v"(m2) : "v"(xx[tt]), "v"(zr[tt][s*4+2]));
          asm("v_pk_mul_f32 %0, %1, %2" : "=v"(m3) : "v"(xx[tt]), "v"(zr[tt][s*4+3]));
          uint32_t p0, p1, p2, p3;
          asm("v_cvt_pk_bf16_f32 %0, %1, %2" : "=v"(p0) : "v"(m0[0]), "v"(m0[1]));
          asm("v_cvt_pk_bf16_f32 %0, %1, %2" : "=v"(p1) : "v"(m1[0]), "v"(m1[1]));
          asm("v_cvt_pk_bf16_f32 %0, %1, %2" : "=v"(p2) : "v"(m2[0]), "v"(m2[1]));
          asm("v_cvt_pk_bf16_f32 %0, %1, %2" : "=v"(p3) : "v"(m3[0]), "v"(m3[1]));
          u32x4v av; av[0] = p0; av[1] = p1; av[2] = p2; av[3] = p3;
          acc[tt] = __builtin_amdgcn_mfma_f32_32x32x16_bf16(
              __builtin_bit_cast(bf16x8, av),
              __builtin_bit_cast(bf16x8, bfr[s]),
              acc[tt], 0, 0, 0);
        }
      }
    }
  };

  // ---------------- pass 1: v = (x1 (x) g) . W1T ----------------
  run_pass(w1t);

  #pragma unroll
  for (int tt = 0; tt < 4; ++tt)
    #pragma unroll
    for (int r = 0; r < 16; ++r) {
      const int rr = (r & 3) + 8 * (r >> 2) + 4 * half;  // C/D row map
      atomicAdd(&vl[(tt * 32 + rr) * 68 + nt * 32 + col], acc[tt][r]);
    }
  __syncthreads();

  // reload zr <- v (f32, full accuracy)
  #pragma unroll
  for (int tt = 0; tt < 4; ++tt) {
    const float* vp = &vl[(tt * 32 + col) * 68];
    #pragma unroll
    for (int s = 0; s < 4; ++s) {
      const int k0 = s * 16 + half * 8;
      f32x4v a = *reinterpret_cast<const f32x4v*>(vp + k0);
      f32x4v b = *reinterpret_cast<const f32x4v*>(vp + k0 + 4);
      zr[tt][s*4+0][0] = a[0]; zr[tt][s*4+0][1] = a[1];
      zr[tt][s*4+1][0] = a[2]; zr[tt][s*4+1][1] = a[3];
      zr[tt][s*4+2][0] = b[0]; zr[tt][s*4+2][1] = b[1];
      zr[tt][s*4+3][0] = b[2]; zr[tt][s*4+3][1] = b[3];
    }
  }
  __syncthreads();
  for (int idx = t; idx < 128 * 68; idx += 512) vl[idx] = 0.0f;
  __syncthreads();

  // ---------------- pass 2: out = (1/8) (x1 (x) v) . W2 ----------------
  run_pass(w2b);

  #pragma unroll
  for (int tt = 0; tt < 4; ++tt)
    #pragma unroll
    for (int r = 0; r < 16; ++r) {
      const int rr = (r & 3) + 8 * (r >> 2) + 4 * half;
      atomicAdd(&vl[(tt * 32 + rr) * 68 + nt * 32 + col], acc[tt][r]);
    }
  __syncthreads();

  for (int idx = t; idx < 128 * 64; idx += 512) {
    int s = idx >> 6, c = idx & 63;
    out[(base + s) * 64 + c] = vl[s * 68 + c] * 0.125f;
  }
}

extern "C" void kernel_launch(void* const* d_in, const int* in_sizes, int n_in,
                              void* d_out, int out_size, void* d_ws, size_t ws_size,
                              hipStream_t stream) {
  const float* x = (const float*)d_in[0];
  const float* g = (const float*)d_in[1];
  const float* W = (const float*)d_in[2];
  float* o = (float*)d_out;
  u16* w1t = (u16*)d_ws;                    // 65*4096 bf16 = 520 KiB
  u16* w2b = w1t + 65 * 4096;               // another 520 KiB (needs ws >= ~1.02 MiB)
  hipLaunchKernelGGL(prep_w, dim3(65), dim3(256), 0, stream, W, w1t, w2b);
  hipLaunchKernelGGL(rquad_main, dim3(256), dim3(512), 0, stream, x, g, w1t, w2b, o);
}